// Round 2
// baseline (11382.735 us; speedup 1.0000x reference)
//
#include <hip/hip_runtime.h>

#define UU 512
#define EE 300
#define VTT 30000
#define SS 64
#define TT 32
#define BB 32

typedef unsigned short u16;
typedef short s8v __attribute__((ext_vector_type(8)));
typedef unsigned short us4 __attribute__((ext_vector_type(4)));
typedef float f4v __attribute__((ext_vector_type(4)));

__device__ __forceinline__ float bf2f(u16 v){
  union { unsigned u; float f; } x; x.u = ((unsigned)v) << 16; return x.f;
}
__device__ __forceinline__ u16 f2bf(float f){
  union { float f; unsigned u; } x; x.f = f;
  unsigned r = x.u + 0x7FFFu + ((x.u >> 16) & 1u);
  return (u16)(r >> 16);
}
__device__ __forceinline__ float sigm(float x){ return 1.f / (1.f + __expf(-x)); }
__device__ __forceinline__ float ftanh(float x){
  float t = __expf(-2.f * fabsf(x));
  float r = (1.f - t) / (1.f + t);
  return x < 0.f ? -r : r;
}

// ---------------- init: zero h-state buffers + first output row (t=0 zero_row) ----
__global__ void k_init(float* __restrict__ h, float* __restrict__ out){
  int i = blockIdx.x * 256 + threadIdx.x;
  if(i < 2*2*BB*UU) h[i] = 0.f;
  if(i < BB*VTT) out[i] = 0.f;
}

// ---------------- Xsrc[tb][k] = bf16(emb_src[source[tb]][k]) ----------------
__global__ void k_embsrc(const float* __restrict__ emb, const int* __restrict__ src,
                         u16* __restrict__ X){
  int i = blockIdx.x * 256 + threadIdx.x;
  if(i >= SS*BB*EE) return;
  int tb = i / EE, k = i - tb*EE;
  X[i] = f2bf(emb[(size_t)src[tb]*EE + k]);
}

// ---------------- generic GEMM-BT: C(M,N) = A_bf16(M,K) @ B_f32(N,K)^T + bias ----
// block 256 = 4 waves (2x2), block tile 128x128, wave tile 64x64, mfma 16x16x32 bf16
__global__ __launch_bounds__(256) void k_bgemm(
    const u16* __restrict__ A, int lda,
    const float* __restrict__ B, int ldb,
    const float* __restrict__ bias,
    float* __restrict__ C, int ldc, int mofs,
    int M, int N, int K){
  int m0 = blockIdx.x * 128;          // m-fastest grid dim: blocks sharing a B-tile adjacent
  int n0 = blockIdx.y * 128;
  int tid = threadIdx.x;
  int lane = tid & 63, wave = tid >> 6;
  int wm = wave >> 1, wn = wave & 1;
  int lm = lane & 15, lq = lane >> 4;
  __shared__ __align__(16) u16 Asl[128*40];
  __shared__ __align__(16) u16 Bsl[128*40];
  f4v acc[4][4];
  #pragma unroll
  for(int i = 0; i < 4; i++)
    #pragma unroll
    for(int j = 0; j < 4; j++) acc[i][j] = (f4v){0.f,0.f,0.f,0.f};
  for(int k0 = 0; k0 < K; k0 += 32){
    __syncthreads();
    #pragma unroll
    for(int p = 0; p < 4; p++){
      int pos = tid + p*256;          // 1024 positions: row = pos>>3 (0..127), kc = pos&7
      int row = pos >> 3, kc = pos & 7;
      int k = k0 + kc*4;
      bool kok = (k + 4) <= K;
      us4 av = (us4){0,0,0,0};
      if(kok && (m0 + row) < M)
        av = *(const us4*)(A + (size_t)(m0+row)*lda + k);
      *(us4*)(Asl + row*40 + kc*4) = av;
      us4 bq = (us4){0,0,0,0};
      if(kok && (n0 + row) < N){
        f4v bv = *(const f4v*)(B + (size_t)(n0+row)*ldb + k);
        bq[0] = f2bf(bv[0]); bq[1] = f2bf(bv[1]); bq[2] = f2bf(bv[2]); bq[3] = f2bf(bv[3]);
      }
      *(us4*)(Bsl + row*40 + kc*4) = bq;
    }
    __syncthreads();
    s8v af[4], bfv[4];
    #pragma unroll
    for(int mi = 0; mi < 4; mi++)
      af[mi] = *(const s8v*)(Asl + (wm*64 + mi*16 + lm)*40 + lq*8);
    #pragma unroll
    for(int nj = 0; nj < 4; nj++)
      bfv[nj] = *(const s8v*)(Bsl + (wn*64 + nj*16 + lm)*40 + lq*8);
    #pragma unroll
    for(int mi = 0; mi < 4; mi++)
      #pragma unroll
      for(int nj = 0; nj < 4; nj++)
        acc[mi][nj] = __builtin_amdgcn_mfma_f32_16x16x32_bf16(af[mi], bfv[nj], acc[mi][nj], 0, 0, 0);
  }
  #pragma unroll
  for(int nj = 0; nj < 4; nj++){
    int n = n0 + wn*64 + nj*16 + lm;
    if(n < N){
      float bv = bias[n];
      #pragma unroll
      for(int mi = 0; mi < 4; mi++){
        #pragma unroll
        for(int rg = 0; rg < 4; rg++){
          int m = m0 + wm*64 + mi*16 + lq*4 + rg;   // C/D: col=lane&15, row=(lane>>4)*4+reg
          if(m < M) C[(size_t)(m + mofs)*ldc + n] = acc[mi][nj][rg] + bv;
        }
      }
    }
  }
}

// ---------------- one encoder step, both directions ----------------
__global__ __launch_bounds__(192) void k_enc_step(int t,
    const float* __restrict__ gi_f, const float* __restrict__ gi_b,
    const float* __restrict__ Whh_f, const float* __restrict__ bhh_f,
    const float* __restrict__ Whh_b, const float* __restrict__ bhh_b,
    float* __restrict__ h, u16* __restrict__ enc){
  int dir = blockIdx.x >> 8;
  int ut  = (blockIdx.x & 255) * 2;
  int tid = threadIdx.x;
  int b = tid & 31, q = tid >> 5;
  int g = q % 3, ul = q / 3;
  int u = ut + ul;
  int par = t & 1;
  int te = dir ? (SS-1-t) : t;
  const float* hin  = h + (dir*2 + par)      * BB*UU;
  float*       hout = h + (dir*2 + (par^1))  * BB*UU;
  const float* Whh = dir ? Whh_b : Whh_f;
  const float* bhh = dir ? bhh_b : bhh_f;
  const float* gi = (dir ? gi_b : gi_f) + (te*BB + b) * 1536;
  const float* wr = Whh + (g*512 + u) * UU;
  __shared__ __align__(16) float hch[32*36];
  __shared__ float ghs[6*32], gis[6*32];
  float acc = 0.f;
  for(int k0 = 0; k0 < UU; k0 += 32){
    __syncthreads();
    for(int i = tid; i < 1024; i += 192){
      int b2 = i >> 5, kk = i & 31;
      hch[b2*36 + kk] = hin[b2*UU + k0 + kk];
    }
    __syncthreads();
    #pragma unroll
    for(int kk = 0; kk < 32; kk += 4){
      f4v x = *(const f4v*)(hch + b*36 + kk);
      f4v w = *(const f4v*)(wr + k0 + kk);
      acc += x[0]*w[0] + x[1]*w[1] + x[2]*w[2] + x[3]*w[3];
    }
  }
  acc += bhh[g*512 + u];
  ghs[q*32 + b] = acc;
  gis[q*32 + b] = gi[g*512 + u];
  __syncthreads();
  if(g == 0){
    float r  = sigm(gis[q*32+b]     + ghs[q*32+b]);
    float z  = sigm(gis[(q+1)*32+b] + ghs[(q+1)*32+b]);
    float n  = ftanh(gis[(q+2)*32+b] + r * ghs[(q+2)*32+b]);
    float hold = hin[b*UU + u];
    float h2 = (1.f - z)*n + z*hold;
    hout[b*UU + u] = h2;
    enc[(size_t)(b*SS + te)*1024 + dir*512 + u] = f2bf(h2);   // enc_bt layout (B,S,2U) bf16
  }
}

// ---------------- state = tanh([hf,hb] @ Wfc^T + bfc) ----------------
__global__ __launch_bounds__(256) void k_encfc(
    const float* __restrict__ h, const float* __restrict__ Wfc,
    const float* __restrict__ bfc, float* __restrict__ st){
  int b = blockIdx.x;
  __shared__ __align__(16) float hc[1024];
  for(int i = threadIdx.x; i < 512; i += 256){
    hc[i]       = h[0*BB*UU + b*UU + i];     // dir0, parity0 (final after 64 steps)
    hc[512 + i] = h[2*BB*UU + b*UU + i];     // dir1, parity0
  }
  __syncthreads();
  for(int u = threadIdx.x; u < 512; u += 256){
    const float* w = Wfc + u*1024;
    float a = 0.f;
    for(int k = 0; k < 1024; k += 4){
      f4v x = *(const f4v*)(hc + k);
      f4v wv = *(const f4v*)(w + k);
      a += x[0]*wv[0] + x[1]*wv[1] + x[2]*wv[2] + x[3]*wv[3];
    }
    st[b*UU + u] = ftanh(a + bfc[u]);
  }
}

// ---------------- decoder attention: q, scores, softmax, ctx ----------------
__global__ __launch_bounds__(256) void k_dec_attn(int t,
    const float* __restrict__ st, const float* __restrict__ attn_W,
    const float* __restrict__ P, const u16* __restrict__ enc,
    const float* __restrict__ emb_trg, const int* __restrict__ target,
    float* __restrict__ ctx, u16* __restrict__ Xl){
  int b = blockIdx.x, tid = threadIdx.x;
  __shared__ __align__(16) float sv[512];
  __shared__ __align__(16) float qv[512];
  __shared__ float wv[64];
  __shared__ float scp[256];
  for(int i = tid; i < 512; i += 256) sv[i] = st[b*UU + i];
  __syncthreads();
  for(int a = tid; a < 512; a += 256){
    const float* w = attn_W + (size_t)a*1536;
    float acc = 0.f;
    for(int k = 0; k < 512; k += 4){
      f4v x = *(const f4v*)(sv + k);
      f4v ww = *(const f4v*)(w + k);
      acc += x[0]*ww[0] + x[1]*ww[1] + x[2]*ww[2] + x[3]*ww[3];
    }
    qv[a] = acc;
  }
  __syncthreads();
  {
    int s = tid >> 2, part = tid & 3;
    const float* Pb = P + (size_t)(b*SS + s)*512 + part*128;
    const float* qp = qv + part*128;
    float ps = 0.f;
    for(int a = 0; a < 128; a++) ps += ftanh(Pb[a] + qp[a]);
    scp[tid] = ps;
  }
  __syncthreads();
  if(tid < 64){
    float sc = scp[tid*4+0] + scp[tid*4+1] + scp[tid*4+2] + scp[tid*4+3];
    float m = sc;
    for(int o = 32; o > 0; o >>= 1) m = fmaxf(m, __shfl_xor(m, o));
    float e = __expf(sc - m);
    float ssum = e;
    for(int o = 32; o > 0; o >>= 1) ssum += __shfl_xor(ssum, o);
    wv[tid] = e / ssum;
  }
  __syncthreads();
  int row = t*BB + b;
  for(int j = tid; j < 1024; j += 256){
    float acc = 0.f;
    for(int s2 = 0; s2 < SS; s2++) acc += wv[s2] * bf2f(enc[(size_t)(b*SS + s2)*1024 + j]);
    ctx[b*1024 + j] = acc;
    Xl[(size_t)row*1836 + 512 + j] = f2bf(acc);
  }
  int tok = target[t*BB + b];
  for(int j = tid; j < EE; j += 256)
    Xl[(size_t)row*1836 + 1536 + j] = f2bf(emb_trg[(size_t)tok*EE + j]);
}

// ---------------- decoder GRU step; writes st_out fp32 + Xl[:,0:512] ----------------
__global__ __launch_bounds__(192) void k_dec_gru(int t,
    const float* __restrict__ st_in, float* __restrict__ st_out,
    const float* __restrict__ ctx,
    const float* __restrict__ emb_trg, const int* __restrict__ target,
    const float* __restrict__ Wih, const float* __restrict__ Whh,
    const float* __restrict__ bih, const float* __restrict__ bhh,
    u16* __restrict__ Xl){
  int ut = blockIdx.x * 2;
  int tid = threadIdx.x;
  int b = tid & 31, q = tid >> 5;
  int g = q % 3, ul = q / 3;
  int u = ut + ul;
  const float* wi = Wih + (size_t)(g*512 + u) * 1324;
  const float* wh = Whh + (size_t)(g*512 + u) * 512;
  __shared__ __align__(16) float xch[32*36];
  __shared__ float As[6*32], Bs[6*32];
  float accA = 0.f, accB = 0.f;   // gi (k<1324) and gh (k>=1324)
  for(int k0 = 0; k0 < 1836; k0 += 32){
    int lim = 1836 - k0; if(lim > 32) lim = 32;
    __syncthreads();
    for(int i = tid; i < 1024; i += 192){
      int b2 = i >> 5, kk = i & 31;
      if(kk < lim){
        int k = k0 + kk;
        float v;
        if(k < EE)        v = emb_trg[(size_t)target[t*BB + b2]*EE + k];
        else if(k < 1324) v = ctx[b2*1024 + (k - EE)];
        else              v = st_in[b2*UU + (k - 1324)];
        xch[b2*36 + kk] = v;
      }
    }
    __syncthreads();
    for(int kk = 0; kk < lim; kk += 4){
      int k = k0 + kk;
      f4v x = *(const f4v*)(xch + b*36 + kk);
      if(k < 1324){
        f4v w = *(const f4v*)(wi + k);
        accA += x[0]*w[0] + x[1]*w[1] + x[2]*w[2] + x[3]*w[3];
      } else {
        f4v w = *(const f4v*)(wh + (k - 1324));
        accB += x[0]*w[0] + x[1]*w[1] + x[2]*w[2] + x[3]*w[3];
      }
    }
  }
  accA += bih[g*512 + u];
  accB += bhh[g*512 + u];
  As[q*32 + b] = accA; Bs[q*32 + b] = accB;
  __syncthreads();
  if(g == 0){
    float r = sigm(As[q*32+b]     + Bs[q*32+b]);
    float z = sigm(As[(q+1)*32+b] + Bs[(q+1)*32+b]);
    float n = ftanh(As[(q+2)*32+b] + r * Bs[(q+2)*32+b]);
    float hold = st_in[b*UU + u];
    float h2 = (1.f - z)*n + z*hold;
    st_out[b*UU + u] = h2;
    Xl[(size_t)(t*BB + b)*1836 + u] = f2bf(h2);
  }
}

extern "C" void kernel_launch(void* const* d_in, const int* in_sizes, int n_in,
                              void* d_out, int out_size, void* d_ws, size_t ws_size,
                              hipStream_t stream){
  (void)in_sizes; (void)n_in; (void)out_size; (void)ws_size;
  const float* emb_src = (const float*)d_in[0];
  const float* emb_trg = (const float*)d_in[1];
  const float* eWih_f  = (const float*)d_in[2];
  const float* eWhh_f  = (const float*)d_in[3];
  const float* ebih_f  = (const float*)d_in[4];
  const float* ebhh_f  = (const float*)d_in[5];
  const float* eWih_b  = (const float*)d_in[6];
  const float* eWhh_b  = (const float*)d_in[7];
  const float* ebih_b  = (const float*)d_in[8];
  const float* ebhh_b  = (const float*)d_in[9];
  const float* Wfc     = (const float*)d_in[10];
  const float* bfc     = (const float*)d_in[11];
  const float* attn_W  = (const float*)d_in[12];
  const float* attn_b  = (const float*)d_in[13];
  const float* dWih    = (const float*)d_in[14];
  const float* dWhh    = (const float*)d_in[15];
  const float* dbih    = (const float*)d_in[16];
  const float* dbhh    = (const float*)d_in[17];
  const float* dWfc    = (const float*)d_in[18];
  const float* dbfc    = (const float*)d_in[19];
  const int* source    = (const int*)d_in[20];
  const int* target    = (const int*)d_in[21];
  float* out = (float*)d_out;
  float* wsf = (float*)d_ws;

  float* gi_f = wsf;                               // 2048 x 1536
  float* gi_b = gi_f + (size_t)2048*1536;
  float* h    = gi_b + (size_t)2048*1536;          // 2 dirs x 2 parity x 32 x 512
  float* st   = h + 4*BB*UU;                       // 2 parity x 32 x 512
  float* P    = st + 2*BB*UU;                      // 2048 x 512
  float* ctx  = P + (size_t)2048*512;              // 32 x 1024
  u16* enc  = (u16*)(ctx + BB*1024);               // (B,S,2U) bf16
  u16* Xl   = enc + (size_t)2048*1024;             // 992 x 1836 bf16
  u16* Xsrc = Xl + (size_t)992*1836;               // 2048 x 300 bf16

  k_init<<<3750, 256, 0, stream>>>(h, out);
  k_embsrc<<<(SS*BB*EE + 255)/256, 256, 0, stream>>>(emb_src, source, Xsrc);
  // gi = Xsrc @ Wih^T + bih  (both directions)
  k_bgemm<<<dim3(16, 12), 256, 0, stream>>>(Xsrc, EE, eWih_f, EE, ebih_f, gi_f, 1536, 0, 2048, 1536, EE);
  k_bgemm<<<dim3(16, 12), 256, 0, stream>>>(Xsrc, EE, eWih_b, EE, ebih_b, gi_b, 1536, 0, 2048, 1536, EE);
  for(int t = 0; t < SS; t++)
    k_enc_step<<<512, 192, 0, stream>>>(t, gi_f, gi_b, eWhh_f, ebhh_f, eWhh_b, ebhh_b, h, enc);
  k_encfc<<<BB, 256, 0, stream>>>(h, Wfc, bfc, st);
  // P[bs][a] = enc_row(bs) . attn_W[a][512:1536] + attn_b[a]
  k_bgemm<<<dim3(16, 4), 256, 0, stream>>>(enc, 1024, attn_W + 512, 1536, attn_b, P, 512, 0, 2048, 512, 1024);
  for(int t = 0; t < TT-1; t++){
    const float* stin = st + (t & 1) * (BB*UU);
    float* stout      = st + ((t+1) & 1) * (BB*UU);
    k_dec_attn<<<BB, 256, 0, stream>>>(t, stin, attn_W, P, enc, emb_trg, target, ctx, Xl);
    k_dec_gru<<<256, 192, 0, stream>>>(t, stin, stout, ctx, emb_trg, target, dWih, dWhh, dbih, dbhh, Xl);
  }
  // logits rows 32..1023 of out: Xl(992x1836) @ dWfc^T + dbfc
  k_bgemm<<<dim3(8, 235), 256, 0, stream>>>(Xl, 1836, dWfc, 1836, dbfc, out, VTT, 32, 992, VTT, 1836);
}